// Round 6
// baseline (11343.367 us; speedup 1.0000x reference)
//
#include <hip/hip_runtime.h>
#include <cstdint>

#define T_STEPS 2048
#define BPG 16       // batches per group
#define GROW 1216    // global h-row bytes: 152 chunks x 8B (150 h + 2 x)
#define LROW 1304    // LDS row pitch bytes (326 dw, %32==6 -> spread banks)
#define KCH 13       // K chunks of 32 (K=416: 400 h + 4 x + 12 zero-by-B)
#define NCHUNK (16*152)
#define NPOS (128*2048)

typedef float f32x4 __attribute__((ext_vector_type(4)));
typedef short s16x8 __attribute__((ext_vector_type(8)));
typedef unsigned int u32x4 __attribute__((ext_vector_type(4)));

__device__ __forceinline__ unsigned int f2bf(float f) {
  unsigned int u = __float_as_uint(f);
  return (u + 0x7FFFu + ((u >> 16) & 1u)) >> 16;
}
__device__ __forceinline__ float sigm(float x) { return 1.0f / (1.0f + __expf(-x)); }
__device__ __forceinline__ float tanh_f(float x) { return 1.0f - 2.0f / (__expf(2.0f * x) + 1.0f); }

#define DPPF(x, ctrl) __int_as_float(__builtin_amdgcn_update_dpp(0, __float_as_int(x), (ctrl), 0xf, 0xf, true))

// in-quad 4x4 transpose + LSTM gate update (validated r3/r5)
__device__ __forceinline__ float gate_update(const f32x4 m, const int q, float& c_st) {
  const bool q0 = (q & 1), q1b = (q & 2);
  float sA = DPPF(q0 ? m[0] : m[1], 0xB1);
  float sB = DPPF(q0 ? m[2] : m[3], 0xB1);
  float n0 = q0 ? sA : m[0];
  float n1 = q0 ? m[1] : sA;
  float n2 = q0 ? sB : m[2];
  float n3 = q0 ? m[3] : sB;
  float tA = DPPF(q1b ? n0 : n2, 0x4E);
  float tB = DPPF(q1b ? n1 : n3, 0x4E);
  float g0 = q1b ? tA : n0;
  float g1 = q1b ? tB : n1;
  float g2 = q1b ? n2 : tA;
  float g3 = q1b ? n3 : tB;
  float cn = sigm(g1) * c_st + sigm(g0) * tanh_f(g2);
  c_st = cn;
  return sigm(g3) * tanh_f(cn);
}

__device__ __forceinline__ void st_sys_b64(void* p, unsigned long long v) {
  asm volatile("global_store_dwordx2 %0, %1, off sc0 sc1" :: "v"(p), "v"(v) : "memory");
}
__device__ __forceinline__ unsigned long long mk2(unsigned int w0, unsigned int w1) {
  return (unsigned long long)w0 | ((unsigned long long)w1 << 32);
}

// ---------------------------------------------------------------------------
// Merged kernel, grid = 490 x 320.
// Blocks 0..79: encoder LSTM, group g=bid&7 (16 batches), wg-slot s=bid>>3.
//   5 waves/wg; wave owns octet o=s*5+wave (units 8o..8o+7). Weights persist
//   in VGPR B-fragments. h published as SELF-STAMPED 8B chunks
//   {3 bf16 units + u16 stamp} (atomic dwordx2, stamp==t+1): no tags, no
//   publish-ack, no poll — consumers speculatively stage the 16x152-chunk
//   tile into LDS, validate stamps, retry (barrier-paced) until fresh.
// Blocks 80..489: uw precompute, then exit.
// ---------------------------------------------------------------------------
__global__ __launch_bounds__(320, 1) void enc_uw_kernel(
    const float* __restrict__ x, const float* __restrict__ W_hh,
    const float* __restrict__ W_ih, const float* __restrict__ b_enc,
    char* __restrict__ hb, float* __restrict__ last_h,
    const float* __restrict__ W_i2h, const float* __restrict__ b_i2h,
    const float* __restrict__ W_dec, const float* __restrict__ b_dec,
    float* __restrict__ uw)
{
  __shared__ char smem[41792];
  const int tid = threadIdx.x;
  const int bid = blockIdx.x;

  if (bid >= 80) {
    // ---------------- uw role ----------------
    float4* Wi = (float4*)smem;                       // [400]
    float4 (*WdT)[4] = (float4(*)[4])(smem + 6400);   // [400][4]
    float* bi = (float*)(smem + 32000);               // [400]
    float* bd = (float*)(smem + 33600);               // [16]
    for (int i = tid; i < 400; i += 320) {
      Wi[i] = *(const float4*)(W_i2h + (size_t)i * 4);
      bi[i] = b_i2h[i];
    }
    for (int i = tid; i < 6400; i += 320) {
      int gq = i & 15, hh = i >> 4;
      ((float*)&WdT[hh][0])[gq] = W_dec[(size_t)gq * 400 + hh];
    }
    if (tid < 16) bd[tid] = b_dec[tid];
    __syncthreads();
#pragma unroll
    for (int rep = 0; rep < 2; ++rep) {
      const int pos = (bid - 80) * 640 + rep * 320 + tid;
      if (pos < NPOS) {
        float4 xv = *(const float4*)(x + (size_t)pos * 4);
        float a[16];
#pragma unroll
        for (int qq = 0; qq < 16; ++qq) a[qq] = bd[qq];
        for (int hh = 0; hh < 400; ++hh) {
          float4 wv = Wi[hh];
          float u = fmaxf(wv.x * xv.x + wv.y * xv.y + wv.z * xv.z + wv.w * xv.w + bi[hh], 0.f);
#pragma unroll
          for (int q4 = 0; q4 < 4; ++q4) {
            float4 d = WdT[hh][q4];
            a[q4 * 4 + 0] = fmaf(d.x, u, a[q4 * 4 + 0]);
            a[q4 * 4 + 1] = fmaf(d.y, u, a[q4 * 4 + 1]);
            a[q4 * 4 + 2] = fmaf(d.z, u, a[q4 * 4 + 2]);
            a[q4 * 4 + 3] = fmaf(d.w, u, a[q4 * 4 + 3]);
          }
        }
        float4* o = (float4*)(uw + (size_t)pos * 16);
#pragma unroll
        for (int q4 = 0; q4 < 4; ++q4)
          o[q4] = make_float4(a[q4 * 4], a[q4 * 4 + 1], a[q4 * 4 + 2], a[q4 * 4 + 3]);
      }
    }
    return;
  }

  // ---------------- encoder role ----------------
  const int g = bid & 7, s = bid >> 3;
  const int wave = tid >> 6, lane = tid & 63;
  const int bbase = g * BPG;
  const int o = s * 5 + wave;                 // octet 0..49
  const int cw = lane & 15, kgrp = lane >> 4;
  const int q = lane & 3, a = (lane >> 2) & 3;
  const int gate = cw & 3, uloc = cw >> 2;
  const int ubase = 8 * o;
  const int batch = 4 * kgrp + q;

  // ---- persistent VGPR B-fragments, canonical k order (identity):
  //      k<400 = W_hh[.][k], 400..403 = W_ih, >=404 = 0
  s16x8 bv0[KCH], bv1[KCH];
#pragma unroll
  for (int tt = 0; tt < 2; ++tt) {
    const int row = gate * 400 + ubase + tt * 4 + uloc;
    const float* wr = W_hh + (size_t)row * 400;
#pragma unroll
    for (int kc = 0; kc < KCH; ++kc) {
      s16x8 bb;
#pragma unroll
      for (int i = 0; i < 8; ++i) {
        const int gk = kc * 32 + kgrp * 8 + i;
        float w;
        if (gk < 400)      w = wr[gk];
        else if (gk < 404) w = W_ih[(size_t)row * 4 + (gk - 400)];
        else               w = 0.f;
        bb[i] = (short)f2bf(w);
      }
      if (tt == 0) bv0[kc] = bb; else bv1[kc] = bb;
    }
  }
  const float bias0 = b_enc[gate * 400 + ubase + uloc];
  const float bias1 = b_enc[gate * 400 + ubase + 4 + uloc];

  // ---- pre-publish step-0 chunks (h=0, stamp=1); x_0 by wg0/wave0/a0 lanes
  {
    if (a < 3) {
      unsigned int w1 = (a == 2) ? 1u : (1u << 16);
      st_sys_b64(hb + (size_t)(bbase + batch) * GROW + (3 * o + a) * 8, mk2(0u, w1));
    }
    if (s == 0 && wave == 0 && a == 0) {
      float4 xv = *(const float4*)(x + (size_t)(bbase + batch) * T_STEPS * 4);
      char* rb = hb + (size_t)(bbase + batch) * GROW;
      st_sys_b64(rb + 150 * 8, mk2(f2bf(xv.x) | (f2bf(xv.y) << 16), f2bf(xv.z) | (1u << 16)));
      st_sys_b64(rb + 151 * 8, mk2(f2bf(xv.w), 1u << 16));
    }
    asm volatile("s_waitcnt expcnt(0)" ::: "memory");
  }

  // ---- loop-invariant staging metadata (8 slots/thread over 2432 chunks)
  int goffs[8], loffs[8];
  bool valid[8], typ2[8];
#pragma unroll
  for (int k = 0; k < 8; ++k) {
    int ci = tid + 320 * k;
    valid[k] = (ci < NCHUNK);
    int cc = valid[k] ? ci : 0;
    int r = cc / 152, c = cc - r * 152;
    goffs[k] = r * GROW + c * 8;
    loffs[k] = r * LROW + c * 8;
    typ2[k] = ((c % 3) == 2);
  }

  int* flags = (int*)(smem + 41728);
  float cs0 = 0.f, cs1 = 0.f;
  int budget = 150000;

  for (int t = 0; t < T_STEPS; ++t) {
    const int p = t & 1;
    const char* gb = hb + (size_t)(p * 128 + bbase) * GROW;
    char* lb = smem + p * 20864;

    float4 xn;
    const bool do_x = (s == 0) && (wave == 0) && (a == 0) && (t + 1 < T_STEPS);
    if (do_x) xn = *(const float4*)(x + ((size_t)(bbase + batch) * T_STEPS + (t + 1)) * 4);

    const unsigned int st = (unsigned int)(t + 1) & 0xffffu;

    // ---- speculative stage + stamp-validate + retry (barrier-paced)
    for (;;) {
      unsigned long long v0, v1, v2, v3, v4, v5, v6, v7;
#define LDC(i)                                                                  \
      asm volatile("global_load_dwordx2 %0, %1, off sc0 sc1"                    \
                   : "=v"(v##i) : "v"(gb + goffs[i]) : "memory");
      LDC(0) LDC(1) LDC(2) LDC(3) LDC(4) LDC(5) LDC(6)
      if (valid[7]) LDC(7)
#undef LDC
      asm volatile("s_waitcnt vmcnt(0)" ::: "memory");
      bool ok = true;
#define CHK(i)                                                                  \
      {                                                                          \
        unsigned int w1 = (unsigned int)(v##i >> 32);                            \
        unsigned int sp = typ2[i] ? (w1 & 0xffffu) : (w1 >> 16);                 \
        ok &= (sp == st);                                                        \
        *(unsigned long long*)(lb + loffs[i]) = v##i;                            \
      }
      CHK(0) CHK(1) CHK(2) CHK(3) CHK(4) CHK(5) CHK(6)
      if (valid[7]) CHK(7)
#undef CHK
      const bool okw = __all(ok);
      if (lane == 0) flags[wave] = okw ? (t + 1) : -1;
      __syncthreads();
      const int tv = t + 1;
      bool all5 = (flags[0] == tv) & (flags[1] == tv) & (flags[2] == tv) &
                  (flags[3] == tv) & (flags[4] == tv);
      if (all5) break;
      if (--budget < 0) break;
      __syncthreads();
    }

    // ---- publish x_{t+1} early (stamped, both chunks by a==0 lane)
    if (do_x) {
      const unsigned int st2 = (unsigned int)(t + 2) & 0xffffu;
      char* rb = hb + (size_t)((p ^ 1) * 128 + bbase + batch) * GROW;
      st_sys_b64(rb + 150 * 8, mk2(f2bf(xn.x) | (f2bf(xn.y) << 16), f2bf(xn.z) | (st2 << 16)));
      st_sys_b64(rb + 151 * 8, mk2(f2bf(xn.w), st2 << 16));
    }

    // ---- fragments from LDS + 26 MFMA (2 col-tiles x 13 chunks)
    const char* lbr = lb + cw * LROW;
    f32x4 acc00 = {bias0, bias0, bias0, bias0};
    f32x4 acc01 = {0.f, 0.f, 0.f, 0.f};
    f32x4 acc10 = {bias1, bias1, bias1, bias1};
    f32x4 acc11 = {0.f, 0.f, 0.f, 0.f};
#pragma unroll
    for (int kc = 0; kc < KCH; ++kc) {
      const char* cp = lbr + (4 * kc + kgrp) * 24;
      unsigned long long d01 = *(const unsigned long long*)cp;
      unsigned long long d23 = *(const unsigned long long*)(cp + 8);
      unsigned long long d45 = *(const unsigned long long*)(cp + 16);
      unsigned int w0 = (unsigned int)d01, w1 = (unsigned int)(d01 >> 32);
      unsigned int w2 = (unsigned int)d23, w3 = (unsigned int)(d23 >> 32);
      unsigned int w4 = (unsigned int)d45;
      unsigned int a01 = w0;
      unsigned int a23 = (w1 & 0xffffu) | (w2 << 16);
      unsigned int a45 = (w2 >> 16) | (w3 << 16);
      unsigned int a67 = w4;
      if (kc == KCH - 1 && kgrp >= 2) {      // k>=400: only x (kgrp2 lo-half) real
        a45 = 0u; a67 = 0u;
        if (kgrp == 3) { a01 = 0u; a23 = 0u; }
      }
      union { u32x4 u; s16x8 s; } cvt;
      cvt.u = (u32x4){a01, a23, a45, a67};
      const s16x8 av = cvt.s;
      if (kc & 1) {
        acc01 = __builtin_amdgcn_mfma_f32_16x16x32_bf16(av, bv0[kc], acc01, 0, 0, 0);
        acc11 = __builtin_amdgcn_mfma_f32_16x16x32_bf16(av, bv1[kc], acc11, 0, 0, 0);
      } else {
        acc00 = __builtin_amdgcn_mfma_f32_16x16x32_bf16(av, bv0[kc], acc00, 0, 0, 0);
        acc10 = __builtin_amdgcn_mfma_f32_16x16x32_bf16(av, bv1[kc], acc10, 0, 0, 0);
      }
    }
    f32x4 m0 = acc00 + acc01;
    f32x4 m1 = acc10 + acc11;

    float hn0 = gate_update(m0, q, cs0);   // unit ubase+a,   batch 4*kgrp+q
    float hn1 = gate_update(m1, q, cs1);   // unit ubase+4+a

    // ---- stamped publish: gather octet into 3 self-stamped 8B chunks
    const int hb0 = (int)f2bf(hn0), hb1 = (int)f2bf(hn1);
    const int base = lane & 51;
    unsigned int g0 = (unsigned int)__shfl(hb0, base);
    unsigned int g1 = (unsigned int)__shfl(hb0, base + 4);
    unsigned int g2 = (unsigned int)__shfl(hb0, base + 8);
    unsigned int g3 = (unsigned int)__shfl(hb0, base + 12);
    unsigned int h0 = (unsigned int)__shfl(hb1, base);
    unsigned int h1 = (unsigned int)__shfl(hb1, base + 4);
    unsigned int h2 = (unsigned int)__shfl(hb1, base + 8);
    unsigned int h3 = (unsigned int)__shfl(hb1, base + 12);
    if (a < 3) {
      const unsigned int st2 = (unsigned int)(t + 2) & 0xffffu;
      unsigned int w0, w1;
      if (a == 0)      { w0 = g0 | (g1 << 16); w1 = g2 | (st2 << 16); }
      else if (a == 1) { w0 = g3 | (h0 << 16); w1 = h1 | (st2 << 16); }
      else             { w0 = h2 | (h3 << 16); w1 = st2; }
      st_sys_b64(hb + (size_t)((p ^ 1) * 128 + bbase + batch) * GROW + (3 * o + a) * 8,
                 mk2(w0, w1));
    }
    if (t == T_STEPS - 1) {
      float* lp = last_h + (size_t)(bbase + batch) * 400 + ubase;
      lp[a] = hn0;
      lp[4 + a] = hn1;
    }
    asm volatile("s_waitcnt expcnt(0)" ::: "memory");
  }
}

// ---------------------------------------------------------------------------
// Fused head (mu/logvar/z/hd0) + decoder LSTM. grid = 128, block = 64.
// ---------------------------------------------------------------------------
__global__ __launch_bounds__(64) void head_dec_kernel(
    const float* __restrict__ last_h, const float* __restrict__ eps,
    const float* __restrict__ W_mu, const float* __restrict__ b_mu,
    const float* __restrict__ W_lv, const float* __restrict__ b_lv,
    const float* __restrict__ W_l2h, const float* __restrict__ b_l2h,
    const float* __restrict__ Whh, const float* __restrict__ uw,
    float* __restrict__ out)
{
  const int b = blockIdx.x, tid = threadIdx.x;
  __shared__ float smu[20], slv[20], sz[20], hd4[4];
  const float4* h4 = (const float4*)(last_h + (size_t)b * 400);
  if (tid < 40) {
    const int o = tid % 20;
    const float4* w4 = (const float4*)((tid < 20 ? W_mu : W_lv) + (size_t)o * 400);
    float s = 0.f;
#pragma unroll 4
    for (int k = 0; k < 100; ++k) {
      float4 a = h4[k], w = w4[k];
      s += a.x * w.x + a.y * w.y + a.z * w.z + a.w * w.w;
    }
    if (tid < 20) { s += b_mu[o]; smu[o] = s; out[512 + b * 20 + o] = s; }
    else          { s += b_lv[o]; slv[o] = s; out[512 + 2560 + b * 20 + o] = s; }
  }
  __syncthreads();
  if (tid < 20) sz[tid] = smu[tid] + eps[b * 20 + tid] * __expf(0.5f * slv[tid]);
  __syncthreads();
  if (tid < 4) {
    float s = b_l2h[tid];
    for (int l = 0; l < 20; ++l) s += W_l2h[tid * 20 + l] * sz[l];
    hd4[tid] = s;
  }
  __syncthreads();
  if (tid < 4) {
    const int j = tid;
    float w[4][4];
#pragma unroll
    for (int gq = 0; gq < 4; ++gq)
#pragma unroll
      for (int k = 0; k < 4; ++k)
        w[gq][k] = Whh[(gq * 4 + j) * 4 + k];
    float h = hd4[j], c = 0.f;
    const float* up = uw + (size_t)b * T_STEPS * 16 + j;
    float pn[4][4];
#pragma unroll
    for (int ss = 0; ss < 4; ++ss) {
      const float* u2 = up + (size_t)ss * 16;
      pn[ss][0] = u2[0]; pn[ss][1] = u2[4]; pn[ss][2] = u2[8]; pn[ss][3] = u2[12];
    }
    for (int tb = 0; tb < T_STEPS; tb += 4) {
#pragma unroll
      for (int ss = 0; ss < 4; ++ss) {
        float c0g = pn[ss][0], c1g = pn[ss][1], c2g = pn[ss][2], c3g = pn[ss][3];
        const int tn = tb + ss + 4;
        if (tn < T_STEPS) {
          const float* u2 = up + (size_t)tn * 16;
          pn[ss][0] = u2[0]; pn[ss][1] = u2[4]; pn[ss][2] = u2[8]; pn[ss][3] = u2[12];
        }
        float h0 = DPPF(h, 0x00), h1 = DPPF(h, 0x55), h2 = DPPF(h, 0xAA), h3 = DPPF(h, 0xFF);
        c0g += w[0][0] * h0 + w[0][1] * h1 + w[0][2] * h2 + w[0][3] * h3;
        c1g += w[1][0] * h0 + w[1][1] * h1 + w[1][2] * h2 + w[1][3] * h3;
        c2g += w[2][0] * h0 + w[2][1] * h1 + w[2][2] * h2 + w[2][3] * h3;
        c3g += w[3][0] * h0 + w[3][1] * h1 + w[3][2] * h2 + w[3][3] * h3;
        c = sigm(c1g) * c + sigm(c0g) * tanh_f(c2g);
        h = sigm(c3g) * tanh_f(c);
      }
    }
    out[b * 4 + j] = h;
  }
}

// ---------------------------------------------------------------------------
// ws layout (bytes):
//   [0,      311296)  hbuf: 2 parities x 128 rows x 1216B stamped chunks (zeroed)
//   [311296, 516096)  last_h: 128 x 400 f32
//   [524288, 17301504) uw: 128 x 2048 x 16 f32   (offset proven in r1-r5)
// ---------------------------------------------------------------------------
extern "C" void kernel_launch(void* const* d_in, const int* in_sizes, int n_in,
                              void* d_out, int out_size, void* d_ws, size_t ws_size,
                              hipStream_t stream)
{
  (void)in_sizes; (void)n_in; (void)out_size; (void)ws_size;
  const float* x        = (const float*)d_in[0];
  const float* eps      = (const float*)d_in[1];
  const float* W_enc_ih = (const float*)d_in[2];
  const float* W_enc_hh = (const float*)d_in[3];
  const float* b_enc    = (const float*)d_in[4];
  const float* W_mu     = (const float*)d_in[5];
  const float* b_mu     = (const float*)d_in[6];
  const float* W_lv     = (const float*)d_in[7];
  const float* b_lv     = (const float*)d_in[8];
  const float* W_l2h    = (const float*)d_in[9];
  const float* b_l2h    = (const float*)d_in[10];
  const float* W_i2h    = (const float*)d_in[11];
  const float* b_i2h    = (const float*)d_in[12];
  const float* W_dec_ih = (const float*)d_in[13];
  const float* W_dec_hh = (const float*)d_in[14];
  const float* b_dec    = (const float*)d_in[15];
  float* out = (float*)d_out;
  char* ws = (char*)d_ws;
  char* hb = ws;
  float* last_h = (float*)(ws + 311296);
  float* uw = (float*)(ws + 524288);

  hipMemsetAsync(ws, 0, 311296, stream);   // zero all stamps (re-poison safe)
  enc_uw_kernel<<<490, 320, 0, stream>>>(
      x, W_enc_hh, W_enc_ih, b_enc, hb, last_h,
      W_i2h, b_i2h, W_dec_ih, b_dec, uw);
  head_dec_kernel<<<128, 64, 0, stream>>>(
      last_h, eps, W_mu, b_mu, W_lv, b_lv, W_l2h, b_l2h, W_dec_hh, uw, out);
}

// Round 7
// 11187.805 us; speedup vs baseline: 1.0139x; 1.0139x over previous
//
#include <hip/hip_runtime.h>
#include <cstdint>

#define T_STEPS 2048
#define BPG 16      // batches per group
#define GROWB 832   // h row bytes (416 bf16: 400 h + 4 x + 12 zero)
#define KCH 13      // K chunks of 32
#define NPOS (128*2048)

typedef float f32x4 __attribute__((ext_vector_type(4)));
typedef short s16x8 __attribute__((ext_vector_type(8)));
typedef unsigned int u32x4 __attribute__((ext_vector_type(4)));

__device__ __forceinline__ unsigned int f2bf(float f) {
  unsigned int u = __float_as_uint(f);
  return (u + 0x7FFFu + ((u >> 16) & 1u)) >> 16;
}
__device__ __forceinline__ float sigm(float x) { return 1.0f / (1.0f + __expf(-x)); }
__device__ __forceinline__ float tanh_f(float x) { return 1.0f - 2.0f / (__expf(2.0f * x) + 1.0f); }

#define DPPF(x, ctrl) __int_as_float(__builtin_amdgcn_update_dpp(0, __float_as_int(x), (ctrl), 0xf, 0xf, true))

// in-quad 4x4 transpose + LSTM gate update (validated r3/r5/r6)
__device__ __forceinline__ float gate_update(const f32x4 m, const int q, float& c_st) {
  const bool q0 = (q & 1), q1b = (q & 2);
  float sA = DPPF(q0 ? m[0] : m[1], 0xB1);
  float sB = DPPF(q0 ? m[2] : m[3], 0xB1);
  float n0 = q0 ? sA : m[0];
  float n1 = q0 ? m[1] : sA;
  float n2 = q0 ? sB : m[2];
  float n3 = q0 ? m[3] : sB;
  float tA = DPPF(q1b ? n0 : n2, 0x4E);
  float tB = DPPF(q1b ? n1 : n3, 0x4E);
  float g0 = q1b ? tA : n0;
  float g1 = q1b ? tB : n1;
  float g2 = q1b ? n2 : tA;
  float g3 = q1b ? n3 : tB;
  float cn = sigm(g1) * c_st + sigm(g0) * tanh_f(g2);
  c_st = cn;
  return sigm(g3) * tanh_f(cn);
}

__device__ __forceinline__ void st_sys_b128(void* p, u32x4 v) {
  asm volatile("global_store_dwordx4 %0, %1, off sc0 sc1" :: "v"(p), "v"(v) : "memory");
}

// ---------------------------------------------------------------------------
// Merged kernel, grid = 490 x 320.
// Blocks 0..79: encoder LSTM, group g=bid&7 (16 batches), wg-slot s=bid>>3.
//   5 autonomous waves/wg (NO barriers, NO LDS in the step loop). Wave owns
//   octet o=s*5+wave (units 8o..8o+7); weights persist in VGPR B-fragments.
//   Per step per wave: bounded poll of 50 per-wave tags (relaxed agent, 8B
//   quantum) -> 13 direct dwordx4 fragment loads (sc0 sc1, MALL/L3-resident)
//   -> 26 MFMA + gate update -> 16B-chunk publish (sc0 sc1) -> vmcnt(0)
//   -> own tag store. ~2 serial MALL RTs/step, zero barriers, zero fences.
// Blocks 80..489: uw precompute, then exit.
// ---------------------------------------------------------------------------
__global__ __launch_bounds__(320, 1) void enc_uw_kernel(
    const float* __restrict__ x, const float* __restrict__ W_hh,
    const float* __restrict__ W_ih, const float* __restrict__ b_enc,
    char* __restrict__ hb, float* __restrict__ last_h,
    int* __restrict__ ctrl,
    const float* __restrict__ W_i2h, const float* __restrict__ b_i2h,
    const float* __restrict__ W_dec, const float* __restrict__ b_dec,
    float* __restrict__ uw)
{
  __shared__ char smem[33664];
  const int tid = threadIdx.x;
  const int bid = blockIdx.x;

  if (bid >= 80) {
    // ---------------- uw role ----------------
    float4* Wi = (float4*)smem;                       // [400]
    float4 (*WdT)[4] = (float4(*)[4])(smem + 6400);   // [400][4]
    float* bi = (float*)(smem + 32000);               // [400]
    float* bd = (float*)(smem + 33600);               // [16]
    for (int i = tid; i < 400; i += 320) {
      Wi[i] = *(const float4*)(W_i2h + (size_t)i * 4);
      bi[i] = b_i2h[i];
    }
    for (int i = tid; i < 6400; i += 320) {
      int gq = i & 15, hh = i >> 4;
      ((float*)&WdT[hh][0])[gq] = W_dec[(size_t)gq * 400 + hh];
    }
    if (tid < 16) bd[tid] = b_dec[tid];
    __syncthreads();
#pragma unroll
    for (int rep = 0; rep < 2; ++rep) {
      const int pos = (bid - 80) * 640 + rep * 320 + tid;
      if (pos < NPOS) {
        float4 xv = *(const float4*)(x + (size_t)pos * 4);
        float a[16];
#pragma unroll
        for (int qq = 0; qq < 16; ++qq) a[qq] = bd[qq];
        for (int hh = 0; hh < 400; ++hh) {
          float4 wv = Wi[hh];
          float u = fmaxf(wv.x * xv.x + wv.y * xv.y + wv.z * xv.z + wv.w * xv.w + bi[hh], 0.f);
#pragma unroll
          for (int q4 = 0; q4 < 4; ++q4) {
            float4 d = WdT[hh][q4];
            a[q4 * 4 + 0] = fmaf(d.x, u, a[q4 * 4 + 0]);
            a[q4 * 4 + 1] = fmaf(d.y, u, a[q4 * 4 + 1]);
            a[q4 * 4 + 2] = fmaf(d.z, u, a[q4 * 4 + 2]);
            a[q4 * 4 + 3] = fmaf(d.w, u, a[q4 * 4 + 3]);
          }
        }
        float4* o = (float4*)(uw + (size_t)pos * 16);
#pragma unroll
        for (int q4 = 0; q4 < 4; ++q4)
          o[q4] = make_float4(a[q4 * 4], a[q4 * 4 + 1], a[q4 * 4 + 2], a[q4 * 4 + 3]);
      }
    }
    return;
  }

  // ---------------- encoder role (autonomous waves) ----------------
  const int g = bid & 7, s = bid >> 3;
  const int wave = tid >> 6, lane = tid & 63;
  const int bbase = g * BPG;
  const int o = s * 5 + wave;                 // octet 0..49
  const int cw = lane & 15, kgrp = lane >> 4;
  const int q = lane & 3, a = (lane >> 2) & 3;
  const int gate = cw & 3, uloc = cw >> 2;
  const int ubase = 8 * o;
  const int batch = 4 * kgrp + q;
  int* tagsG = ctrl + g * 256;                // 50 per-wave tags per group

  // ---- persistent VGPR B-fragments; publish layout is perm-interleaved:
  //      chunk element i of octet og = canonical unit 8*og + perm[i];
  //      elements 400..403 = x (canonical), >=404 = 0
  const int perm[8] = {0, 4, 1, 5, 2, 6, 3, 7};
  s16x8 bv0[KCH], bv1[KCH];
#pragma unroll
  for (int tt = 0; tt < 2; ++tt) {
    const int row = gate * 400 + ubase + tt * 4 + uloc;
    const float* wr = W_hh + (size_t)row * 400;
#pragma unroll
    for (int kc = 0; kc < KCH; ++kc) {
      s16x8 bb;
#pragma unroll
      for (int i = 0; i < 8; ++i) {
        const int gk = kc * 32 + kgrp * 8 + i;
        float w;
        if (gk < 400)      w = wr[(size_t)(kc * 4 + kgrp) * 8 + perm[i]];
        else if (gk < 404) w = W_ih[(size_t)row * 4 + (gk - 400)];
        else               w = 0.f;
        bb[i] = (short)f2bf(w);
      }
      if (tt == 0) bv0[kc] = bb; else bv1[kc] = bb;
    }
  }
  const float bias0 = b_enc[gate * 400 + ubase + uloc];
  const float bias1 = b_enc[gate * 400 + ubase + 4 + uloc];

  // ---- initial publication: x_0 (wg0/wave0/a0 lanes); h_0 = memset zeros
  if (s == 0 && wave == 0 && a == 0) {
    float4 xv = *(const float4*)(x + (size_t)(bbase + batch) * T_STEPS * 4);
    u32x4 xp = {f2bf(xv.x) | (f2bf(xv.y) << 16), f2bf(xv.z) | (f2bf(xv.w) << 16), 0u, 0u};
    st_sys_b128(hb + (size_t)(bbase + batch) * GROWB + 800, xp);
  }
  asm volatile("s_waitcnt vmcnt(0)" ::: "memory");
  if (lane == 0)
    __hip_atomic_store(&tagsG[o], 1, __ATOMIC_RELAXED, __HIP_MEMORY_SCOPE_AGENT);

  float cs0 = 0.f, cs1 = 0.f;
  int budget = 4000000;   // global poll-iteration budget: degrade, never hang

  for (int t = 0; t < T_STEPS; ++t) {
    const int p = t & 1;
    const char* gb = hb + (size_t)(p * 128 + bbase) * GROWB;

    float4 xn;
    const bool do_x = (s == 0) && (wave == 0) && (a == 0) && (t + 1 < T_STEPS);
    if (do_x) xn = *(const float4*)(x + ((size_t)(bbase + batch) * T_STEPS + (t + 1)) * 4);

    // ---- bounded poll: all 50 per-wave tags >= t+1 (8B relaxed agent loads)
    {
      const int tgt = t + 1;
      const unsigned long long* tp = (const unsigned long long*)tagsG;
      bool ok;
      do {
        unsigned long long v = ~0ull;
        if (lane < 25)
          v = __hip_atomic_load(&tp[lane], __ATOMIC_RELAXED, __HIP_MEMORY_SCOPE_AGENT);
        ok = (lane >= 25) || (((int)(unsigned int)v >= tgt) && ((int)(v >> 32) >= tgt));
        if (--budget < 0) break;
      } while (!__all(ok));
    }

    // ---- direct fragment loads: lane (cw,kgrp) reads A[row=cw][k=kc*32+kgrp*8]
    const char* Ab = gb + cw * GROWB + kgrp * 16;
    s16x8 av0, av1, av2, av3, av4, av5, av6, av7, av8, av9, av10, av11, av12;
    asm volatile(
        "global_load_dwordx4 %0, %13, off sc0 sc1\n\t"
        "global_load_dwordx4 %1, %13, off offset:64 sc0 sc1\n\t"
        "global_load_dwordx4 %2, %13, off offset:128 sc0 sc1\n\t"
        "global_load_dwordx4 %3, %13, off offset:192 sc0 sc1\n\t"
        "global_load_dwordx4 %4, %13, off offset:256 sc0 sc1\n\t"
        "global_load_dwordx4 %5, %13, off offset:320 sc0 sc1\n\t"
        "global_load_dwordx4 %6, %13, off offset:384 sc0 sc1\n\t"
        "global_load_dwordx4 %7, %13, off offset:448 sc0 sc1\n\t"
        "global_load_dwordx4 %8, %13, off offset:512 sc0 sc1\n\t"
        "global_load_dwordx4 %9, %13, off offset:576 sc0 sc1\n\t"
        "global_load_dwordx4 %10, %13, off offset:640 sc0 sc1\n\t"
        "global_load_dwordx4 %11, %13, off offset:704 sc0 sc1\n\t"
        "global_load_dwordx4 %12, %13, off offset:768 sc0 sc1\n\t"
        "s_waitcnt vmcnt(0)"
        : "=&v"(av0), "=&v"(av1), "=&v"(av2), "=&v"(av3), "=&v"(av4),
          "=&v"(av5), "=&v"(av6), "=&v"(av7), "=&v"(av8), "=&v"(av9),
          "=&v"(av10), "=&v"(av11), "=&v"(av12)
        : "v"(Ab)
        : "memory");
    __builtin_amdgcn_sched_barrier(0);

    // ---- 26 MFMA (2 col-tiles x 13 chunks, dual accumulation chains)
    f32x4 acc00 = {bias0, bias0, bias0, bias0};
    f32x4 acc01 = {0.f, 0.f, 0.f, 0.f};
    f32x4 acc10 = {bias1, bias1, bias1, bias1};
    f32x4 acc11 = {0.f, 0.f, 0.f, 0.f};
#define MM(av, i)                                                                \
    if ((i) & 1) {                                                               \
      acc01 = __builtin_amdgcn_mfma_f32_16x16x32_bf16(av, bv0[i], acc01, 0, 0, 0); \
      acc11 = __builtin_amdgcn_mfma_f32_16x16x32_bf16(av, bv1[i], acc11, 0, 0, 0); \
    } else {                                                                     \
      acc00 = __builtin_amdgcn_mfma_f32_16x16x32_bf16(av, bv0[i], acc00, 0, 0, 0); \
      acc10 = __builtin_amdgcn_mfma_f32_16x16x32_bf16(av, bv1[i], acc10, 0, 0, 0); \
    }
    MM(av0, 0) MM(av1, 1) MM(av2, 2) MM(av3, 3) MM(av4, 4) MM(av5, 5) MM(av6, 6)
    MM(av7, 7) MM(av8, 8) MM(av9, 9) MM(av10, 10) MM(av11, 11) MM(av12, 12)
#undef MM
    f32x4 m0 = acc00 + acc01;
    f32x4 m1 = acc10 + acc11;

    float hn0 = gate_update(m0, q, cs0);   // unit ubase+a,   batch 4*kgrp+q
    float hn1 = gate_update(m1, q, cs1);   // unit ubase+4+a

    // ---- publish: gather octet into one 16B chunk per batch row (a==0 lanes)
    const int hb0 = (int)f2bf(hn0), hb1 = (int)f2bf(hn1);
    const int base = lane & 51;           // clear the a-bits
    unsigned int w0 = (unsigned int)__shfl(hb0, base) |
                      ((unsigned int)__shfl(hb1, base) << 16);
    unsigned int w1 = (unsigned int)__shfl(hb0, base + 4) |
                      ((unsigned int)__shfl(hb1, base + 4) << 16);
    unsigned int w2 = (unsigned int)__shfl(hb0, base + 8) |
                      ((unsigned int)__shfl(hb1, base + 8) << 16);
    unsigned int w3 = (unsigned int)__shfl(hb0, base + 12) |
                      ((unsigned int)__shfl(hb1, base + 12) << 16);
    if (a == 0) {
      char* rp = hb + (size_t)((p ^ 1) * 128 + bbase + batch) * GROWB + o * 16;
      u32x4 val = {w0, w1, w2, w3};
      st_sys_b128(rp, val);
      if (do_x) {
        u32x4 xp = {f2bf(xn.x) | (f2bf(xn.y) << 16), f2bf(xn.z) | (f2bf(xn.w) << 16), 0u, 0u};
        st_sys_b128(rp - o * 16 + 800, xp);
      }
    }
    if (t == T_STEPS - 1) {
      float* lp = last_h + (size_t)(bbase + batch) * 400 + ubase;
      lp[a] = hn0;
      lp[4 + a] = hn1;
    }
    asm volatile("s_waitcnt vmcnt(0)" ::: "memory");   // drain own publishes
    if (lane == 0)
      __hip_atomic_store(&tagsG[o], t + 2, __ATOMIC_RELAXED, __HIP_MEMORY_SCOPE_AGENT);
  }
}

// ---------------------------------------------------------------------------
// Fused head (mu/logvar/z/hd0) + decoder LSTM. grid = 128, block = 64.
// ---------------------------------------------------------------------------
__global__ __launch_bounds__(64) void head_dec_kernel(
    const float* __restrict__ last_h, const float* __restrict__ eps,
    const float* __restrict__ W_mu, const float* __restrict__ b_mu,
    const float* __restrict__ W_lv, const float* __restrict__ b_lv,
    const float* __restrict__ W_l2h, const float* __restrict__ b_l2h,
    const float* __restrict__ Whh, const float* __restrict__ uw,
    float* __restrict__ out)
{
  const int b = blockIdx.x, tid = threadIdx.x;
  __shared__ float smu[20], slv[20], sz[20], hd4[4];
  const float4* h4 = (const float4*)(last_h + (size_t)b * 400);
  if (tid < 40) {
    const int o = tid % 20;
    const float4* w4 = (const float4*)((tid < 20 ? W_mu : W_lv) + (size_t)o * 400);
    float s = 0.f;
#pragma unroll 4
    for (int k = 0; k < 100; ++k) {
      float4 a = h4[k], w = w4[k];
      s += a.x * w.x + a.y * w.y + a.z * w.z + a.w * w.w;
    }
    if (tid < 20) { s += b_mu[o]; smu[o] = s; out[512 + b * 20 + o] = s; }
    else          { s += b_lv[o]; slv[o] = s; out[512 + 2560 + b * 20 + o] = s; }
  }
  __syncthreads();
  if (tid < 20) sz[tid] = smu[tid] + eps[b * 20 + tid] * __expf(0.5f * slv[tid]);
  __syncthreads();
  if (tid < 4) {
    float s = b_l2h[tid];
    for (int l = 0; l < 20; ++l) s += W_l2h[tid * 20 + l] * sz[l];
    hd4[tid] = s;
  }
  __syncthreads();
  if (tid < 4) {
    const int j = tid;
    float w[4][4];
#pragma unroll
    for (int gq = 0; gq < 4; ++gq)
#pragma unroll
      for (int k = 0; k < 4; ++k)
        w[gq][k] = Whh[(gq * 4 + j) * 4 + k];
    float h = hd4[j], c = 0.f;
    const float* up = uw + (size_t)b * T_STEPS * 16 + j;
    float pn[4][4];
#pragma unroll
    for (int ss = 0; ss < 4; ++ss) {
      const float* u2 = up + (size_t)ss * 16;
      pn[ss][0] = u2[0]; pn[ss][1] = u2[4]; pn[ss][2] = u2[8]; pn[ss][3] = u2[12];
    }
    for (int tb = 0; tb < T_STEPS; tb += 4) {
#pragma unroll
      for (int ss = 0; ss < 4; ++ss) {
        float c0g = pn[ss][0], c1g = pn[ss][1], c2g = pn[ss][2], c3g = pn[ss][3];
        const int tn = tb + ss + 4;
        if (tn < T_STEPS) {
          const float* u2 = up + (size_t)tn * 16;
          pn[ss][0] = u2[0]; pn[ss][1] = u2[4]; pn[ss][2] = u2[8]; pn[ss][3] = u2[12];
        }
        float h0 = DPPF(h, 0x00), h1 = DPPF(h, 0x55), h2 = DPPF(h, 0xAA), h3 = DPPF(h, 0xFF);
        c0g += w[0][0] * h0 + w[0][1] * h1 + w[0][2] * h2 + w[0][3] * h3;
        c1g += w[1][0] * h0 + w[1][1] * h1 + w[1][2] * h2 + w[1][3] * h3;
        c2g += w[2][0] * h0 + w[2][1] * h1 + w[2][2] * h2 + w[2][3] * h3;
        c3g += w[3][0] * h0 + w[3][1] * h1 + w[3][2] * h2 + w[3][3] * h3;
        c = sigm(c1g) * c + sigm(c0g) * tanh_f(c2g);
        h = sigm(c3g) * tanh_f(c);
      }
    }
    out[b * 4 + j] = h;
  }
}

// ---------------------------------------------------------------------------
// ws layout (bytes):
//   [0,      8192)   tags: 8 groups x 1024B (50 ints used per group)
//   [16384,  229376) hbuf: 2 parities x 128 rows x 832B (zeroed -> h_0 = 0)
//   [229376, 434176) last_h: 128 x 400 f32
//   [524288, ...)    uw: 128 x 2048 x 16 f32
// ---------------------------------------------------------------------------
extern "C" void kernel_launch(void* const* d_in, const int* in_sizes, int n_in,
                              void* d_out, int out_size, void* d_ws, size_t ws_size,
                              hipStream_t stream)
{
  (void)in_sizes; (void)n_in; (void)out_size; (void)ws_size;
  const float* x        = (const float*)d_in[0];
  const float* eps      = (const float*)d_in[1];
  const float* W_enc_ih = (const float*)d_in[2];
  const float* W_enc_hh = (const float*)d_in[3];
  const float* b_enc    = (const float*)d_in[4];
  const float* W_mu     = (const float*)d_in[5];
  const float* b_mu     = (const float*)d_in[6];
  const float* W_lv     = (const float*)d_in[7];
  const float* b_lv     = (const float*)d_in[8];
  const float* W_l2h    = (const float*)d_in[9];
  const float* b_l2h    = (const float*)d_in[10];
  const float* W_i2h    = (const float*)d_in[11];
  const float* b_i2h    = (const float*)d_in[12];
  const float* W_dec_ih = (const float*)d_in[13];
  const float* W_dec_hh = (const float*)d_in[14];
  const float* b_dec    = (const float*)d_in[15];
  float* out = (float*)d_out;
  char* ws = (char*)d_ws;
  int* ctrl = (int*)ws;
  char* hb = ws + 16384;
  float* last_h = (float*)(ws + 229376);
  float* uw = (float*)(ws + 524288);

  hipMemsetAsync(ws, 0, 229376, stream);   // tags + h_0 zeros + row-tail zeros
  enc_uw_kernel<<<490, 320, 0, stream>>>(
      x, W_enc_hh, W_enc_ih, b_enc, hb, last_h, ctrl,
      W_i2h, b_i2h, W_dec_ih, b_dec, uw);
  head_dec_kernel<<<128, 64, 0, stream>>>(
      last_h, eps, W_mu, b_mu, W_lv, b_lv, W_l2h, b_l2h, W_dec_hh, uw, out);
}

// Round 9
// 9320.741 us; speedup vs baseline: 1.2170x; 1.2003x over previous
//
#include <hip/hip_runtime.h>
#include <cstdint>

#define T_STEPS 2048
#define BPG 16      // batches per group
#define GROWB 832   // h row bytes (416 bf16: 400 h + 4 x + 12 zero) = 52 x 16B
#define LROW 848    // LDS row pitch (padded +16B vs bank conflicts)
#define LBUF (16 * LROW)
#define KCH 13      // K chunks of 32
#define NPOS (128*2048)

typedef float f32x4 __attribute__((ext_vector_type(4)));
typedef short s16x8 __attribute__((ext_vector_type(8)));
typedef unsigned int u32x4 __attribute__((ext_vector_type(4)));

__device__ __forceinline__ unsigned int f2bf(float f) {
  unsigned int u = __float_as_uint(f);
  return (u + 0x7FFFu + ((u >> 16) & 1u)) >> 16;
}
__device__ __forceinline__ float sigm(float x) { return 1.0f / (1.0f + __expf(-x)); }
__device__ __forceinline__ float tanh_f(float x) { return 1.0f - 2.0f / (__expf(2.0f * x) + 1.0f); }

#define DPPF(x, ctrl) __int_as_float(__builtin_amdgcn_update_dpp(0, __float_as_int(x), (ctrl), 0xf, 0xf, true))

// in-quad 4x4 transpose + LSTM gate update (validated r3/r5/r6/r7)
__device__ __forceinline__ float gate_update(const f32x4 m, const int q, float& c_st) {
  const bool q0 = (q & 1), q1b = (q & 2);
  float sA = DPPF(q0 ? m[0] : m[1], 0xB1);
  float sB = DPPF(q0 ? m[2] : m[3], 0xB1);
  float n0 = q0 ? sA : m[0];
  float n1 = q0 ? m[1] : sA;
  float n2 = q0 ? sB : m[2];
  float n3 = q0 ? m[3] : sB;
  float tA = DPPF(q1b ? n0 : n2, 0x4E);
  float tB = DPPF(q1b ? n1 : n3, 0x4E);
  float g0 = q1b ? tA : n0;
  float g1 = q1b ? tB : n1;
  float g2 = q1b ? n2 : tA;
  float g3 = q1b ? n3 : tB;
  float cn = sigm(g1) * c_st + sigm(g0) * tanh_f(g2);
  c_st = cn;
  return sigm(g3) * tanh_f(cn);
}

// ---- proven system-scope primitives (sc0 sc1 = MALL coherence point)
__device__ __forceinline__ void st128_sys(void* p, u32x4 v) {
  asm volatile("global_store_dwordx4 %0, %1, off sc0 sc1" :: "v"(p), "v"(v) : "memory");
}
__device__ __forceinline__ void st32_sys(void* p, unsigned int v) {
  asm volatile("global_store_dword %0, %1, off sc0 sc1" :: "v"(p), "v"(v) : "memory");
}
__device__ __forceinline__ unsigned long long ld64_sys_wait(const void* p) {
  unsigned long long v;
  asm volatile("global_load_dwordx2 %0, %1, off sc0 sc1\n\ts_waitcnt vmcnt(0)"
               : "=v"(v) : "v"(p) : "memory");
  return v;
}
__device__ __forceinline__ unsigned long long ld64_sys_issue(const void* p) {
  unsigned long long v;
  asm volatile("global_load_dwordx2 %0, %1, off sc0 sc1" : "=v"(v) : "v"(p) : "memory");
  return v;
}
__device__ __forceinline__ u32x4 ld128_sys_issue(const void* p) {
  u32x4 v;
  asm volatile("global_load_dwordx4 %0, %1, off sc0 sc1" : "=v"(v) : "v"(p) : "memory");
  return v;
}

// ---------------------------------------------------------------------------
// Merged kernel, grid = 490 x 320 (static roles, r5-proven).
// Blocks 0..79: encoder LSTM, group g=bid&7 (16 batches), wg-slot s=bid>>3.
//   5 waves/wg, wave owns octet o=s*5+wave (units 8o..8o+7, perm-interleaved).
//   Weights persist in VGPR B-fragments. Per step:
//     [poll 50 per-wave tags, skipped if overlapped pre-poll hit]
//     -> cooperative 13.3KB stage into LDS[parity] -> ONE barrier
//     -> 26 MFMA + gate update
//     -> publish 16B chunks + ISSUE next-step tag loads + vmcnt(0) (drains
//        both) -> own tag store -> evaluate pre-poll.
//   Single barrier/step is safe: LDS is per-parity; the last reader of a
//   parity buffer provably passed the intervening barrier.
// Blocks 80..489: uw precompute, then exit.
// ---------------------------------------------------------------------------
__global__ __launch_bounds__(320, 1) void enc_uw_kernel(
    const float* __restrict__ x, const float* __restrict__ W_hh,
    const float* __restrict__ W_ih, const float* __restrict__ b_enc,
    char* __restrict__ hb, float* __restrict__ last_h,
    int* __restrict__ ctrl,
    const float* __restrict__ W_i2h, const float* __restrict__ b_i2h,
    const float* __restrict__ W_dec, const float* __restrict__ b_dec,
    float* __restrict__ uw)
{
  __shared__ char smem[33664];
  const int tid = threadIdx.x;
  const int bid = blockIdx.x;

  if (bid >= 80) {
    // ---------------- uw role (r5-proven) ----------------
    float4* Wi = (float4*)smem;                       // [400]
    float4 (*WdT)[4] = (float4(*)[4])(smem + 6400);   // [400][4]
    float* bi = (float*)(smem + 32000);               // [400]
    float* bd = (float*)(smem + 33600);               // [16]
    for (int i = tid; i < 400; i += 320) {
      Wi[i] = *(const float4*)(W_i2h + (size_t)i * 4);
      bi[i] = b_i2h[i];
    }
    for (int i = tid; i < 6400; i += 320) {
      int gq = i & 15, hh = i >> 4;
      ((float*)&WdT[hh][0])[gq] = W_dec[(size_t)gq * 400 + hh];
    }
    if (tid < 16) bd[tid] = b_dec[tid];
    __syncthreads();
#pragma unroll
    for (int rep = 0; rep < 2; ++rep) {
      const int pos = (bid - 80) * 640 + rep * 320 + tid;
      if (pos < NPOS) {
        float4 xv = *(const float4*)(x + (size_t)pos * 4);
        float a[16];
#pragma unroll
        for (int qq = 0; qq < 16; ++qq) a[qq] = bd[qq];
        for (int hh = 0; hh < 400; ++hh) {
          float4 wv = Wi[hh];
          float u = fmaxf(wv.x * xv.x + wv.y * xv.y + wv.z * xv.z + wv.w * xv.w + bi[hh], 0.f);
#pragma unroll
          for (int q4 = 0; q4 < 4; ++q4) {
            float4 d = WdT[hh][q4];
            a[q4 * 4 + 0] = fmaf(d.x, u, a[q4 * 4 + 0]);
            a[q4 * 4 + 1] = fmaf(d.y, u, a[q4 * 4 + 1]);
            a[q4 * 4 + 2] = fmaf(d.z, u, a[q4 * 4 + 2]);
            a[q4 * 4 + 3] = fmaf(d.w, u, a[q4 * 4 + 3]);
          }
        }
        float4* o = (float4*)(uw + (size_t)pos * 16);
#pragma unroll
        for (int q4 = 0; q4 < 4; ++q4)
          o[q4] = make_float4(a[q4 * 4], a[q4 * 4 + 1], a[q4 * 4 + 2], a[q4 * 4 + 3]);
      }
    }
    return;
  }

  // ---------------- encoder role ----------------
  const int g = bid & 7, s = bid >> 3;
  const int wave = tid >> 6, lane = tid & 63;
  const int bbase = g * BPG;
  const int o = s * 5 + wave;                 // octet 0..49
  const int cw = lane & 15, kgrp = lane >> 4;
  const int q = lane & 3, a = (lane >> 2) & 3;
  const int gate = cw & 3, uloc = cw >> 2;
  const int ubase = 8 * o;
  const int batch = 4 * kgrp + q;
  int* tagsG = ctrl + g * 256;                // 50 per-wave tags per group
  const unsigned long long* tp = (const unsigned long long*)tagsG;

  // ---- persistent VGPR B-fragments (r7-proven perm-interleaved layout)
  const int perm[8] = {0, 4, 1, 5, 2, 6, 3, 7};
  s16x8 bv0[KCH], bv1[KCH];
#pragma unroll
  for (int tt = 0; tt < 2; ++tt) {
    const int row = gate * 400 + ubase + tt * 4 + uloc;
    const float* wr = W_hh + (size_t)row * 400;
#pragma unroll
    for (int kc = 0; kc < KCH; ++kc) {
      s16x8 bb;
#pragma unroll
      for (int i = 0; i < 8; ++i) {
        const int gk = kc * 32 + kgrp * 8 + i;
        float w;
        if (gk < 400)      w = wr[(size_t)(kc * 4 + kgrp) * 8 + perm[i]];
        else if (gk < 404) w = W_ih[(size_t)row * 4 + (gk - 400)];
        else               w = 0.f;
        bb[i] = (short)f2bf(w);
      }
      if (tt == 0) bv0[kc] = bb; else bv1[kc] = bb;
    }
  }
  const float bias0 = b_enc[gate * 400 + ubase + uloc];
  const float bias1 = b_enc[gate * 400 + ubase + 4 + uloc];

  // ---- initial publication: x_0 (wg0/wave0/a0 lanes); h_0 = memset zeros
  if (s == 0 && wave == 0 && a == 0) {
    float4 xv = *(const float4*)(x + (size_t)(bbase + batch) * T_STEPS * 4);
    u32x4 xp = {f2bf(xv.x) | (f2bf(xv.y) << 16), f2bf(xv.z) | (f2bf(xv.w) << 16), 0u, 0u};
    st128_sys(hb + (size_t)(bbase + batch) * GROWB + 800, xp);
  }
  asm volatile("s_waitcnt vmcnt(0)" ::: "memory");
  if (lane == 0) st32_sys(&tagsG[o], 1u);

  // ---- loop-invariant staging metadata: 832 chunks over 320 threads
  int gof0, gof1, gof2, lof0, lof1, lof2;
  bool val3;
  {
    const int i0 = tid, i1 = tid + 320, i2v = tid + 640;
    val3 = (i2v < 832);
    const int i2 = val3 ? i2v : 0;
    gof0 = (i0 / 52) * GROWB + (i0 % 52) * 16;
    lof0 = (i0 / 52) * LROW  + (i0 % 52) * 16;
    gof1 = (i1 / 52) * GROWB + (i1 % 52) * 16;
    lof1 = (i1 / 52) * LROW  + (i1 % 52) * 16;
    gof2 = (i2 / 52) * GROWB + (i2 % 52) * 16;
    lof2 = (i2 / 52) * LROW  + (i2 % 52) * 16;
  }

  float cs0 = 0.f, cs1 = 0.f;
  int budget = 8000000;     // bounded: degrade to wrong-answer, never hang
  bool pre_ok = false;

  for (int t = 0; t < T_STEPS; ++t) {
    const int p = t & 1;
    const char* gb = hb + (size_t)(p * 128 + bbase) * GROWB;
    char* lb = smem + p * LBUF;

    float4 xn;
    const bool do_x = (s == 0) && (wave == 0) && (a == 0) && (t + 1 < T_STEPS);
    if (do_x) xn = *(const float4*)(x + ((size_t)(bbase + batch) * T_STEPS + (t + 1)) * 4);

    // ---- poll all 50 per-wave tags >= t+1 (skipped when pre-poll hit)
    if (!pre_ok) {
      const int tgt = t + 1;
      bool ok;
      do {
        unsigned long long v = ~0ull;
        if (lane < 25) v = ld64_sys_wait(tp + lane);
        ok = (lane >= 25) || (((int)(unsigned int)v >= tgt) && ((int)(v >> 32) >= tgt));
        if (--budget < 0) break;
      } while (!__all(ok));
    }

    // ---- cooperative stage: 16 rows x 832B -> LDS[parity] (2-3 x 16B/thread)
    {
      u32x4 v0 = ld128_sys_issue(gb + gof0);
      u32x4 v1 = ld128_sys_issue(gb + gof1);
      u32x4 v2;
      if (val3) v2 = ld128_sys_issue(gb + gof2);
      asm volatile("s_waitcnt vmcnt(0)" ::: "memory");
      *(u32x4*)(lb + lof0) = v0;
      *(u32x4*)(lb + lof1) = v1;
      if (val3) *(u32x4*)(lb + lof2) = v2;
    }
    __syncthreads();   // the ONLY barrier per step

    // ---- fragments from LDS + 26 MFMA (2 col-tiles x 13 chunks)
    const char* At = lb + cw * LROW + kgrp * 16;
    f32x4 acc00 = {bias0, bias0, bias0, bias0};
    f32x4 acc01 = {0.f, 0.f, 0.f, 0.f};
    f32x4 acc10 = {bias1, bias1, bias1, bias1};
    f32x4 acc11 = {0.f, 0.f, 0.f, 0.f};
#pragma unroll
    for (int kc = 0; kc < KCH; ++kc) {
      const s16x8 avv = *(const s16x8*)(At + kc * 64);
      if (kc & 1) {
        acc01 = __builtin_amdgcn_mfma_f32_16x16x32_bf16(avv, bv0[kc], acc01, 0, 0, 0);
        acc11 = __builtin_amdgcn_mfma_f32_16x16x32_bf16(avv, bv1[kc], acc11, 0, 0, 0);
      } else {
        acc00 = __builtin_amdgcn_mfma_f32_16x16x32_bf16(avv, bv0[kc], acc00, 0, 0, 0);
        acc10 = __builtin_amdgcn_mfma_f32_16x16x32_bf16(avv, bv1[kc], acc10, 0, 0, 0);
      }
    }
    f32x4 m0 = acc00 + acc01;
    f32x4 m1 = acc10 + acc11;

    float hn0 = gate_update(m0, q, cs0);   // unit ubase+a,   batch 4*kgrp+q
    float hn1 = gate_update(m1, q, cs1);   // unit ubase+4+a

    // ---- publish (16B chunk per batch row, a==0 lanes) + overlapped pre-poll
    const int hb0 = (int)f2bf(hn0), hb1 = (int)f2bf(hn1);
    const int base = lane & 51;           // clear the a-bits
    unsigned int w0 = (unsigned int)__shfl(hb0, base) |
                      ((unsigned int)__shfl(hb1, base) << 16);
    unsigned int w1 = (unsigned int)__shfl(hb0, base + 4) |
                      ((unsigned int)__shfl(hb1, base + 4) << 16);
    unsigned int w2 = (unsigned int)__shfl(hb0, base + 8) |
                      ((unsigned int)__shfl(hb1, base + 8) << 16);
    unsigned int w3 = (unsigned int)__shfl(hb0, base + 12) |
                      ((unsigned int)__shfl(hb1, base + 12) << 16);
    if (a == 0) {
      char* rp = hb + (size_t)((p ^ 1) * 128 + bbase + batch) * GROWB + o * 16;
      u32x4 val = {w0, w1, w2, w3};
      st128_sys(rp, val);
      if (do_x) {
        u32x4 xp = {f2bf(xn.x) | (f2bf(xn.y) << 16), f2bf(xn.z) | (f2bf(xn.w) << 16), 0u, 0u};
        st128_sys(rp - o * 16 + 800, xp);
      }
    }
    if (t == T_STEPS - 1) {
      float* lp = last_h + (size_t)(bbase + batch) * 400 + ubase;
      lp[a] = hn0;
      lp[4 + a] = hn1;
    }
    // issue next-step tag loads NOW (flight overlaps the store drain)
    unsigned long long pv = ~0ull;
    if (lane < 25) pv = ld64_sys_issue(tp + lane);
    asm volatile("s_waitcnt vmcnt(0)" : "+v"(pv) :: "memory");  // drains stores+load
    __builtin_amdgcn_sched_barrier(0);
    const int nt = t + 2;
    if (lane == 0) st32_sys(&tagsG[o], (unsigned int)nt);
    {
      bool ok;
      if (lane >= 25) ok = true;
      else {
        int lo = (int)(unsigned int)pv, hi = (int)(pv >> 32);
        if (lane == (o >> 1)) { if (o & 1) hi = nt; else lo = nt; }  // own slot
        ok = (lo >= nt) && (hi >= nt);
      }
      pre_ok = __all(ok);
    }
  }
}

// ---------------------------------------------------------------------------
// Fused head (mu/logvar/z/hd0) + decoder LSTM. grid = 128, block = 64.
// ---------------------------------------------------------------------------
__global__ __launch_bounds__(64) void head_dec_kernel(
    const float* __restrict__ last_h, const float* __restrict__ eps,
    const float* __restrict__ W_mu, const float* __restrict__ b_mu,
    const float* __restrict__ W_lv, const float* __restrict__ b_lv,
    const float* __restrict__ W_l2h, const float* __restrict__ b_l2h,
    const float* __restrict__ Whh, const float* __restrict__ uw,
    float* __restrict__ out)
{
  const int b = blockIdx.x, tid = threadIdx.x;
  __shared__ float smu[20], slv[20], sz[20], hd4[4];
  const float4* h4 = (const float4*)(last_h + (size_t)b * 400);
  if (tid < 40) {
    const int o = tid % 20;
    const float4* w4 = (const float4*)((tid < 20 ? W_mu : W_lv) + (size_t)o * 400);
    float s = 0.f;
#pragma unroll 4
    for (int k = 0; k < 100; ++k) {
      float4 a = h4[k], w = w4[k];
      s += a.x * w.x + a.y * w.y + a.z * w.z + a.w * w.w;
    }
    if (tid < 20) { s += b_mu[o]; smu[o] = s; out[512 + b * 20 + o] = s; }
    else          { s += b_lv[o]; slv[o] = s; out[512 + 2560 + b * 20 + o] = s; }
  }
  __syncthreads();
  if (tid < 20) sz[tid] = smu[tid] + eps[b * 20 + tid] * __expf(0.5f * slv[tid]);
  __syncthreads();
  if (tid < 4) {
    float s = b_l2h[tid];
    for (int l = 0; l < 20; ++l) s += W_l2h[tid * 20 + l] * sz[l];
    hd4[tid] = s;
  }
  __syncthreads();
  if (tid < 4) {
    const int j = tid;
    float w[4][4];
#pragma unroll
    for (int gq = 0; gq < 4; ++gq)
#pragma unroll
      for (int k = 0; k < 4; ++k)
        w[gq][k] = Whh[(gq * 4 + j) * 4 + k];
    float h = hd4[j], c = 0.f;
    const float* up = uw + (size_t)b * T_STEPS * 16 + j;
    float pn[4][4];
#pragma unroll
    for (int ss = 0; ss < 4; ++ss) {
      const float* u2 = up + (size_t)ss * 16;
      pn[ss][0] = u2[0]; pn[ss][1] = u2[4]; pn[ss][2] = u2[8]; pn[ss][3] = u2[12];
    }
    for (int tb = 0; tb < T_STEPS; tb += 4) {
#pragma unroll
      for (int ss = 0; ss < 4; ++ss) {
        float c0g = pn[ss][0], c1g = pn[ss][1], c2g = pn[ss][2], c3g = pn[ss][3];
        const int tn = tb + ss + 4;
        if (tn < T_STEPS) {
          const float* u2 = up + (size_t)tn * 16;
          pn[ss][0] = u2[0]; pn[ss][1] = u2[4]; pn[ss][2] = u2[8]; pn[ss][3] = u2[12];
        }
        float h0 = DPPF(h, 0x00), h1 = DPPF(h, 0x55), h2 = DPPF(h, 0xAA), h3 = DPPF(h, 0xFF);
        c0g += w[0][0] * h0 + w[0][1] * h1 + w[0][2] * h2 + w[0][3] * h3;
        c1g += w[1][0] * h0 + w[1][1] * h1 + w[1][2] * h2 + w[1][3] * h3;
        c2g += w[2][0] * h0 + w[2][1] * h1 + w[2][2] * h2 + w[2][3] * h3;
        c3g += w[3][0] * h0 + w[3][1] * h1 + w[3][2] * h2 + w[3][3] * h3;
        c = sigm(c1g) * c + sigm(c0g) * tanh_f(c2g);
        h = sigm(c3g) * tanh_f(c);
      }
    }
    out[b * 4 + j] = h;
  }
}

// ---------------------------------------------------------------------------
// ws layout (bytes):
//   [0,      8192)   tags: 8 groups x 1024B (50 ints used per group)
//   [16384,  229376) hbuf: 2 parities x 128 rows x 832B (zeroed -> h_0 = 0)
//   [229376, 434176) last_h: 128 x 400 f32
//   [524288, ...)    uw: 128 x 2048 x 16 f32
// ---------------------------------------------------------------------------
extern "C" void kernel_launch(void* const* d_in, const int* in_sizes, int n_in,
                              void* d_out, int out_size, void* d_ws, size_t ws_size,
                              hipStream_t stream)
{
  (void)in_sizes; (void)n_in; (void)out_size; (void)ws_size;
  const float* x        = (const float*)d_in[0];
  const float* eps      = (const float*)d_in[1];
  const float* W_enc_ih = (const float*)d_in[2];
  const float* W_enc_hh = (const float*)d_in[3];
  const float* b_enc    = (const float*)d_in[4];
  const float* W_mu     = (const float*)d_in[5];
  const float* b_mu     = (const float*)d_in[6];
  const float* W_lv     = (const float*)d_in[7];
  const float* b_lv     = (const float*)d_in[8];
  const float* W_l2h    = (const float*)d_in[9];
  const float* b_l2h    = (const float*)d_in[10];
  const float* W_i2h    = (const float*)d_in[11];
  const float* b_i2h    = (const float*)d_in[12];
  const float* W_dec_ih = (const float*)d_in[13];
  const float* W_dec_hh = (const float*)d_in[14];
  const float* b_dec    = (const float*)d_in[15];
  float* out = (float*)d_out;
  char* ws = (char*)d_ws;
  int* ctrl = (int*)ws;
  char* hb = ws + 16384;
  float* last_h = (float*)(ws + 229376);
  float* uw = (float*)(ws + 524288);

  hipMemsetAsync(ws, 0, 229376, stream);   // tags + h_0 zeros + row-tail zeros
  enc_uw_kernel<<<490, 320, 0, stream>>>(
      x, W_enc_hh, W_enc_ih, b_enc, hb, last_h, ctrl,
      W_i2h, b_i2h, W_dec_ih, b_dec, uw);
  head_dec_kernel<<<128, 64, 0, stream>>>(
      last_h, eps, W_mu, b_mu, W_lv, b_lv, W_l2h, b_l2h, W_dec_hh, uw, out);
}

// Round 10
// 9112.309 us; speedup vs baseline: 1.2448x; 1.0229x over previous
//
#include <hip/hip_runtime.h>
#include <cstdint>

#define T_STEPS 2048
#define BPG 16       // batches per group
#define GROW 1216    // global h-row bytes: 152 chunks x 8B (150 h + 2 x)
#define LROW 1304    // LDS row pitch bytes
#define KCH 13       // K chunks of 32 (K=416: 400 h + 4 x + 12 zero-by-B)
#define NCHUNK (16*152)
#define NPOS (128*2048)

typedef float f32x4 __attribute__((ext_vector_type(4)));
typedef short s16x8 __attribute__((ext_vector_type(8)));
typedef unsigned int u32x4 __attribute__((ext_vector_type(4)));

__device__ __forceinline__ unsigned int f2bf(float f) {
  unsigned int u = __float_as_uint(f);
  return (u + 0x7FFFu + ((u >> 16) & 1u)) >> 16;
}
__device__ __forceinline__ float sigm(float x) { return 1.0f / (1.0f + __expf(-x)); }
__device__ __forceinline__ float tanh_f(float x) { return 1.0f - 2.0f / (__expf(2.0f * x) + 1.0f); }

#define DPPF(x, ctrl) __int_as_float(__builtin_amdgcn_update_dpp(0, __float_as_int(x), (ctrl), 0xf, 0xf, true))

// in-quad 4x4 transpose + LSTM gate update (validated r3/r5/r6)
__device__ __forceinline__ float gate_update(const f32x4 m, const int q, float& c_st) {
  const bool q0 = (q & 1), q1b = (q & 2);
  float sA = DPPF(q0 ? m[0] : m[1], 0xB1);
  float sB = DPPF(q0 ? m[2] : m[3], 0xB1);
  float n0 = q0 ? sA : m[0];
  float n1 = q0 ? m[1] : sA;
  float n2 = q0 ? sB : m[2];
  float n3 = q0 ? m[3] : sB;
  float tA = DPPF(q1b ? n0 : n2, 0x4E);
  float tB = DPPF(q1b ? n1 : n3, 0x4E);
  float g0 = q1b ? tA : n0;
  float g1 = q1b ? tB : n1;
  float g2 = q1b ? n2 : tA;
  float g3 = q1b ? n3 : tB;
  float cn = sigm(g1) * c_st + sigm(g0) * tanh_f(g2);
  c_st = cn;
  return sigm(g3) * tanh_f(cn);
}

__device__ __forceinline__ void st_sys_b64(void* p, unsigned long long v) {
  asm volatile("global_store_dwordx2 %0, %1, off sc0 sc1" :: "v"(p), "v"(v) : "memory");
}
__device__ __forceinline__ unsigned long long ld_sys_b64_issue(const void* p) {
  unsigned long long v;
  asm volatile("global_load_dwordx2 %0, %1, off sc0 sc1" : "=v"(v) : "v"(p) : "memory");
  return v;
}
__device__ __forceinline__ unsigned long long mk2(unsigned int w0, unsigned int w1) {
  return (unsigned long long)w0 | ((unsigned long long)w1 << 32);
}

// ---------------------------------------------------------------------------
// Merged kernel, grid = 490 x 320.
// Blocks 0..79: encoder LSTM, group g=bid&7 (16 batches), wg-slot s=bid>>3.
//   5 waves/wg; wave owns octet o=s*5+wave. Weights persist in VGPR
//   B-fragments. h published as SELF-STAMPED 8B chunks {3 bf16 + u16 stamp}
//   (stamp = t+2 for h_{t+1}): no tags, no drains, no polls. Consumers stage
//   the 16x152-chunk tile speculatively; EACH THREAD re-reads only ITS OWN
//   stale chunks until stamps match (8B-granular retry, no barriers in the
//   retry loop), writes each chunk to LDS once, then ONE barrier -> MFMA.
// Blocks 80..489: uw precompute, then exit.
// ---------------------------------------------------------------------------
__global__ __launch_bounds__(320, 1) void enc_uw_kernel(
    const float* __restrict__ x, const float* __restrict__ W_hh,
    const float* __restrict__ W_ih, const float* __restrict__ b_enc,
    char* __restrict__ hb, float* __restrict__ last_h,
    const float* __restrict__ W_i2h, const float* __restrict__ b_i2h,
    const float* __restrict__ W_dec, const float* __restrict__ b_dec,
    float* __restrict__ uw)
{
  __shared__ char smem[41728];
  const int tid = threadIdx.x;
  const int bid = blockIdx.x;

  if (bid >= 80) {
    // ---------------- uw role (r5/r6-proven) ----------------
    float4* Wi = (float4*)smem;                       // [400]
    float4 (*WdT)[4] = (float4(*)[4])(smem + 6400);   // [400][4]
    float* bi = (float*)(smem + 32000);               // [400]
    float* bd = (float*)(smem + 33600);               // [16]
    for (int i = tid; i < 400; i += 320) {
      Wi[i] = *(const float4*)(W_i2h + (size_t)i * 4);
      bi[i] = b_i2h[i];
    }
    for (int i = tid; i < 6400; i += 320) {
      int gq = i & 15, hh = i >> 4;
      ((float*)&WdT[hh][0])[gq] = W_dec[(size_t)gq * 400 + hh];
    }
    if (tid < 16) bd[tid] = b_dec[tid];
    __syncthreads();
#pragma unroll
    for (int rep = 0; rep < 2; ++rep) {
      const int pos = (bid - 80) * 640 + rep * 320 + tid;
      if (pos < NPOS) {
        float4 xv = *(const float4*)(x + (size_t)pos * 4);
        float a[16];
#pragma unroll
        for (int qq = 0; qq < 16; ++qq) a[qq] = bd[qq];
        for (int hh = 0; hh < 400; ++hh) {
          float4 wv = Wi[hh];
          float u = fmaxf(wv.x * xv.x + wv.y * xv.y + wv.z * xv.z + wv.w * xv.w + bi[hh], 0.f);
#pragma unroll
          for (int q4 = 0; q4 < 4; ++q4) {
            float4 d = WdT[hh][q4];
            a[q4 * 4 + 0] = fmaf(d.x, u, a[q4 * 4 + 0]);
            a[q4 * 4 + 1] = fmaf(d.y, u, a[q4 * 4 + 1]);
            a[q4 * 4 + 2] = fmaf(d.z, u, a[q4 * 4 + 2]);
            a[q4 * 4 + 3] = fmaf(d.w, u, a[q4 * 4 + 3]);
          }
        }
        float4* o = (float4*)(uw + (size_t)pos * 16);
#pragma unroll
        for (int q4 = 0; q4 < 4; ++q4)
          o[q4] = make_float4(a[q4 * 4], a[q4 * 4 + 1], a[q4 * 4 + 2], a[q4 * 4 + 3]);
      }
    }
    return;
  }

  // ---------------- encoder role ----------------
  const int g = bid & 7, s = bid >> 3;
  const int wave = tid >> 6, lane = tid & 63;
  const int bbase = g * BPG;
  const int o = s * 5 + wave;                 // octet 0..49
  const int cw = lane & 15, kgrp = lane >> 4;
  const int q = lane & 3, a = (lane >> 2) & 3;
  const int gate = cw & 3, uloc = cw >> 2;
  const int ubase = 8 * o;
  const int batch = 4 * kgrp + q;

  // ---- persistent VGPR B-fragments, canonical k order (r6-verified):
  //      k<400 = W_hh[.][k], 400..403 = W_ih, >=404 = 0
  s16x8 bv0[KCH], bv1[KCH];
#pragma unroll
  for (int tt = 0; tt < 2; ++tt) {
    const int row = gate * 400 + ubase + tt * 4 + uloc;
    const float* wr = W_hh + (size_t)row * 400;
#pragma unroll
    for (int kc = 0; kc < KCH; ++kc) {
      s16x8 bb;
#pragma unroll
      for (int i = 0; i < 8; ++i) {
        const int gk = kc * 32 + kgrp * 8 + i;
        float w;
        if (gk < 400)      w = wr[gk];
        else if (gk < 404) w = W_ih[(size_t)row * 4 + (gk - 400)];
        else               w = 0.f;
        bb[i] = (short)f2bf(w);
      }
      if (tt == 0) bv0[kc] = bb; else bv1[kc] = bb;
    }
  }
  const float bias0 = b_enc[gate * 400 + ubase + uloc];
  const float bias1 = b_enc[gate * 400 + ubase + 4 + uloc];

  // ---- pre-publish step-0 chunks (h=0, stamp=1); x_0 by wg0/wave0/a0 lanes
  {
    if (a < 3) {
      unsigned int w1 = (a == 2) ? 1u : (1u << 16);
      st_sys_b64(hb + (size_t)(bbase + batch) * GROW + (3 * o + a) * 8, mk2(0u, w1));
    }
    if (s == 0 && wave == 0 && a == 0) {
      float4 xv = *(const float4*)(x + (size_t)(bbase + batch) * T_STEPS * 4);
      char* rb = hb + (size_t)(bbase + batch) * GROW;
      st_sys_b64(rb + 150 * 8, mk2(f2bf(xv.x) | (f2bf(xv.y) << 16), f2bf(xv.z) | (1u << 16)));
      st_sys_b64(rb + 151 * 8, mk2(f2bf(xv.w), 1u << 16));
    }
    asm volatile("s_waitcnt expcnt(0)" ::: "memory");
  }

  // ---- loop-invariant staging metadata (8 slots/thread over 2432 chunks)
  int goffs[8], loffs[8];
  bool valid[8], typ2[8];
#pragma unroll
  for (int k = 0; k < 8; ++k) {
    int ci = tid + 320 * k;
    valid[k] = (ci < NCHUNK);
    int cc = valid[k] ? ci : 0;
    int r = cc / 152, c = cc - r * 152;
    goffs[k] = r * GROW + c * 8;
    loffs[k] = r * LROW + c * 8;
    typ2[k] = ((c % 3) == 2);
  }

  float cs0 = 0.f, cs1 = 0.f;
  int budget = 2000000;    // bounded: degrade to wrong-answer, never hang

  for (int t = 0; t < T_STEPS; ++t) {
    const int p = t & 1;
    const char* gb = hb + (size_t)(p * 128 + bbase) * GROW;
    char* lb = smem + p * 20864;

    float4 xn;
    const bool do_x = (s == 0) && (wave == 0) && (a == 0) && (t + 1 < T_STEPS);
    if (do_x) xn = *(const float4*)(x + ((size_t)(bbase + batch) * T_STEPS + (t + 1)) * 4);

    const unsigned int st = (unsigned int)(t + 1) & 0xffffu;

    // ---- speculative stage, PER-THREAD PARTIAL RETRY (8B-granular, no
    //      barriers, no flags): reload only chunks whose stamp != t+1.
    {
      unsigned long long v0, v1, v2, v3, v4, v5, v6, v7;
      bool d0 = false, d1 = false, d2 = false, d3 = false,
           d4 = false, d5 = false, d6 = false, d7 = !valid[7];
      for (;;) {
#define ISS(i)  if (!d##i) v##i = ld_sys_b64_issue(gb + goffs[i]);
        ISS(0) ISS(1) ISS(2) ISS(3) ISS(4) ISS(5) ISS(6) ISS(7)
#undef ISS
        asm volatile("s_waitcnt vmcnt(0)" ::: "memory");
        bool all = true;
#define CHK(i)                                                                   \
        if (!d##i) {                                                             \
          unsigned int w1 = (unsigned int)(v##i >> 32);                          \
          unsigned int sp = typ2[i] ? (w1 & 0xffffu) : (w1 >> 16);               \
          if (sp == st) {                                                        \
            *(unsigned long long*)(lb + loffs[i]) = v##i;                        \
            d##i = true;                                                         \
          } else all = false;                                                    \
        }
        CHK(0) CHK(1) CHK(2) CHK(3) CHK(4) CHK(5) CHK(6) CHK(7)
#undef CHK
        if (all) break;
        if (--budget < 0) break;
      }
    }
    __syncthreads();   // the ONLY barrier per step

    // ---- publish x_{t+1} early (stamped, both chunks by the do_x lanes)
    if (do_x) {
      const unsigned int st2 = (unsigned int)(t + 2) & 0xffffu;
      char* rb = hb + (size_t)((p ^ 1) * 128 + bbase + batch) * GROW;
      st_sys_b64(rb + 150 * 8, mk2(f2bf(xn.x) | (f2bf(xn.y) << 16), f2bf(xn.z) | (st2 << 16)));
      st_sys_b64(rb + 151 * 8, mk2(f2bf(xn.w), st2 << 16));
    }

    // ---- fragments from LDS + 26 MFMA (r6-verified unpack)
    const char* lbr = lb + cw * LROW;
    f32x4 acc00 = {bias0, bias0, bias0, bias0};
    f32x4 acc01 = {0.f, 0.f, 0.f, 0.f};
    f32x4 acc10 = {bias1, bias1, bias1, bias1};
    f32x4 acc11 = {0.f, 0.f, 0.f, 0.f};
#pragma unroll
    for (int kc = 0; kc < KCH; ++kc) {
      const char* cp = lbr + (4 * kc + kgrp) * 24;
      unsigned long long d01 = *(const unsigned long long*)cp;
      unsigned long long d23 = *(const unsigned long long*)(cp + 8);
      unsigned long long d45 = *(const unsigned long long*)(cp + 16);
      unsigned int w0 = (unsigned int)d01, w1 = (unsigned int)(d01 >> 32);
      unsigned int w2 = (unsigned int)d23, w3 = (unsigned int)(d23 >> 32);
      unsigned int w4 = (unsigned int)d45;
      unsigned int a01 = w0;
      unsigned int a23 = (w1 & 0xffffu) | (w2 << 16);
      unsigned int a45 = (w2 >> 16) | (w3 << 16);
      unsigned int a67 = w4;
      if (kc == KCH - 1 && kgrp >= 2) {      // k>=400: only x (kgrp2 lo-half) real
        a45 = 0u; a67 = 0u;
        if (kgrp == 3) { a01 = 0u; a23 = 0u; }
      }
      union { u32x4 u; s16x8 s; } cvt;
      cvt.u = (u32x4){a01, a23, a45, a67};
      const s16x8 av = cvt.s;
      if (kc & 1) {
        acc01 = __builtin_amdgcn_mfma_f32_16x16x32_bf16(av, bv0[kc], acc01, 0, 0, 0);
        acc11 = __builtin_amdgcn_mfma_f32_16x16x32_bf16(av, bv1[kc], acc11, 0, 0, 0);
      } else {
        acc00 = __builtin_amdgcn_mfma_f32_16x16x32_bf16(av, bv0[kc], acc00, 0, 0, 0);
        acc10 = __builtin_amdgcn_mfma_f32_16x16x32_bf16(av, bv1[kc], acc10, 0, 0, 0);
      }
    }
    f32x4 m0 = acc00 + acc01;
    f32x4 m1 = acc10 + acc11;

    float hn0 = gate_update(m0, q, cs0);   // unit ubase+a,   batch 4*kgrp+q
    float hn1 = gate_update(m1, q, cs1);   // unit ubase+4+a

    // ---- stamped publish: gather octet into 3 self-stamped 8B chunks
    const int hb0 = (int)f2bf(hn0), hb1 = (int)f2bf(hn1);
    const int base = lane & 51;
    unsigned int g0 = (unsigned int)__shfl(hb0, base);
    unsigned int g1 = (unsigned int)__shfl(hb0, base + 4);
    unsigned int g2 = (unsigned int)__shfl(hb0, base + 8);
    unsigned int g3 = (unsigned int)__shfl(hb0, base + 12);
    unsigned int h0 = (unsigned int)__shfl(hb1, base);
    unsigned int h1 = (unsigned int)__shfl(hb1, base + 4);
    unsigned int h2 = (unsigned int)__shfl(hb1, base + 8);
    unsigned int h3 = (unsigned int)__shfl(hb1, base + 12);
    if (a < 3) {
      const unsigned int st2 = (unsigned int)(t + 2) & 0xffffu;
      unsigned int w0, w1;
      if (a == 0)      { w0 = g0 | (g1 << 16); w1 = g2 | (st2 << 16); }
      else if (a == 1) { w0 = g3 | (h0 << 16); w1 = h1 | (st2 << 16); }
      else             { w0 = h2 | (h3 << 16); w1 = st2; }
      st_sys_b64(hb + (size_t)((p ^ 1) * 128 + bbase + batch) * GROW + (3 * o + a) * 8,
                 mk2(w0, w1));
    }
    if (t == T_STEPS - 1) {
      float* lp = last_h + (size_t)(bbase + batch) * 400 + ubase;
      lp[a] = hn0;
      lp[4 + a] = hn1;
    }
    asm volatile("s_waitcnt expcnt(0)" ::: "memory");   // VGPR-reuse safety only
  }
}

// ---------------------------------------------------------------------------
// Fused head (mu/logvar/z/hd0) + decoder LSTM. grid = 128, block = 64.
// ---------------------------------------------------------------------------
__global__ __launch_bounds__(64) void head_dec_kernel(
    const float* __restrict__ last_h, const float* __restrict__ eps,
    const float* __restrict__ W_mu, const float* __restrict__ b_mu,
    const float* __restrict__ W_lv, const float* __restrict__ b_lv,
    const float* __restrict__ W_l2h, const float* __restrict__ b_l2h,
    const float* __restrict__ Whh, const float* __restrict__ uw,
    float* __restrict__ out)
{
  const int b = blockIdx.x, tid = threadIdx.x;
  __shared__ float smu[20], slv[20], sz[20], hd4[4];
  const float4* h4 = (const float4*)(last_h + (size_t)b * 400);
  if (tid < 40) {
    const int o = tid % 20;
    const float4* w4 = (const float4*)((tid < 20 ? W_mu : W_lv) + (size_t)o * 400);
    float s = 0.f;
#pragma unroll 4
    for (int k = 0; k < 100; ++k) {
      float4 a = h4[k], w = w4[k];
      s += a.x * w.x + a.y * w.y + a.z * w.z + a.w * w.w;
    }
    if (tid < 20) { s += b_mu[o]; smu[o] = s; out[512 + b * 20 + o] = s; }
    else          { s += b_lv[o]; slv[o] = s; out[512 + 2560 + b * 20 + o] = s; }
  }
  __syncthreads();
  if (tid < 20) sz[tid] = smu[tid] + eps[b * 20 + tid] * __expf(0.5f * slv[tid]);
  __syncthreads();
  if (tid < 4) {
    float s = b_l2h[tid];
    for (int l = 0; l < 20; ++l) s += W_l2h[tid * 20 + l] * sz[l];
    hd4[tid] = s;
  }
  __syncthreads();
  if (tid < 4) {
    const int j = tid;
    float w[4][4];
#pragma unroll
    for (int gq = 0; gq < 4; ++gq)
#pragma unroll
      for (int k = 0; k < 4; ++k)
        w[gq][k] = Whh[(gq * 4 + j) * 4 + k];
    float h = hd4[j], c = 0.f;
    const float* up = uw + (size_t)b * T_STEPS * 16 + j;
    float pn[4][4];
#pragma unroll
    for (int ss = 0; ss < 4; ++ss) {
      const float* u2 = up + (size_t)ss * 16;
      pn[ss][0] = u2[0]; pn[ss][1] = u2[4]; pn[ss][2] = u2[8]; pn[ss][3] = u2[12];
    }
    for (int tb = 0; tb < T_STEPS; tb += 4) {
#pragma unroll
      for (int ss = 0; ss < 4; ++ss) {
        float c0g = pn[ss][0], c1g = pn[ss][1], c2g = pn[ss][2], c3g = pn[ss][3];
        const int tn = tb + ss + 4;
        if (tn < T_STEPS) {
          const float* u2 = up + (size_t)tn * 16;
          pn[ss][0] = u2[0]; pn[ss][1] = u2[4]; pn[ss][2] = u2[8]; pn[ss][3] = u2[12];
        }
        float h0 = DPPF(h, 0x00), h1 = DPPF(h, 0x55), h2 = DPPF(h, 0xAA), h3 = DPPF(h, 0xFF);
        c0g += w[0][0] * h0 + w[0][1] * h1 + w[0][2] * h2 + w[0][3] * h3;
        c1g += w[1][0] * h0 + w[1][1] * h1 + w[1][2] * h2 + w[1][3] * h3;
        c2g += w[2][0] * h0 + w[2][1] * h1 + w[2][2] * h2 + w[2][3] * h3;
        c3g += w[3][0] * h0 + w[3][1] * h1 + w[3][2] * h2 + w[3][3] * h3;
        c = sigm(c1g) * c + sigm(c0g) * tanh_f(c2g);
        h = sigm(c3g) * tanh_f(c);
      }
    }
    out[b * 4 + j] = h;
  }
}

// ---------------------------------------------------------------------------
// ws layout (bytes):
//   [0,      311296)  hbuf: 2 parities x 128 rows x 1216B stamped chunks (zeroed)
//   [311296, 516096)  last_h: 128 x 400 f32
//   [524288, ...)     uw: 128 x 2048 x 16 f32
// ---------------------------------------------------------------------------
extern "C" void kernel_launch(void* const* d_in, const int* in_sizes, int n_in,
                              void* d_out, int out_size, void* d_ws, size_t ws_size,
                              hipStream_t stream)
{
  (void)in_sizes; (void)n_in; (void)out_size; (void)ws_size;
  const float* x        = (const float*)d_in[0];
  const float* eps      = (const float*)d_in[1];
  const float* W_enc_ih = (const float*)d_in[2];
  const float* W_enc_hh = (const float*)d_in[3];
  const float* b_enc    = (const float*)d_in[4];
  const float* W_mu     = (const float*)d_in[5];
  const float* b_mu     = (const float*)d_in[6];
  const float* W_lv     = (const float*)d_in[7];
  const float* b_lv     = (const float*)d_in[8];
  const float* W_l2h    = (const float*)d_in[9];
  const float* b_l2h    = (const float*)d_in[10];
  const float* W_i2h    = (const float*)d_in[11];
  const float* b_i2h    = (const float*)d_in[12];
  const float* W_dec_ih = (const float*)d_in[13];
  const float* W_dec_hh = (const float*)d_in[14];
  const float* b_dec    = (const float*)d_in[15];
  float* out = (float*)d_out;
  char* ws = (char*)d_ws;
  char* hb = ws;
  float* last_h = (float*)(ws + 311296);
  float* uw = (float*)(ws + 524288);

  hipMemsetAsync(ws, 0, 311296, stream);   // zero all stamps (replay-safe)
  enc_uw_kernel<<<490, 320, 0, stream>>>(
      x, W_enc_hh, W_enc_ih, b_enc, hb, last_h,
      W_i2h, b_i2h, W_dec_ih, b_dec, uw);
  head_dec_kernel<<<128, 64, 0, stream>>>(
      last_h, eps, W_mu, b_mu, W_lv, b_lv, W_l2h, b_l2h, W_dec_hh, uw, out);
}